// Round 6
// baseline (969.178 us; speedup 1.0000x reference)
//
#include <hip/hip_runtime.h>

// Problem constants
#define Bz 2048
#define Tz 336
#define Fz 10
#define H1 70
#define H2 21

typedef __attribute__((ext_vector_type(8))) short short8;   // 8 bf16 = 4 VGPR
typedef __attribute__((ext_vector_type(4))) float float4v;  // MFMA acc

#define MFMA16(a, b, c) __builtin_amdgcn_mfma_f32_16x16x32_bf16((a), (b), (c), 0, 0, 0)

__device__ __forceinline__ float sigf(float x) {
    return 1.0f / (1.0f + __expf(-x));
}
__device__ __forceinline__ float tanhfast(float x) {
    float t = __expf(2.0f * x);
    return 1.0f - 2.0f / (t + 1.0f);
}
__device__ __forceinline__ unsigned short f2bf(float v) {
    unsigned int u = __float_as_uint(v);
    u += 0x7FFFu + ((u >> 16) & 1u);
    return (unsigned short)(u >> 16);
}
__device__ __forceinline__ float bf2f(unsigned short s) {
    return __uint_as_float(((unsigned int)s) << 16);
}

// Fragment-order LDS offset (in shorts) for (index-in-16 m, k):
// (m, k) lives at ((k>>3)*16 + m)*8 + (k&7)
__device__ __forceinline__ int frag_off(int m, int k) {
    return (k >> 3) * 128 + m * 8 + (k & 7);
}

// ---------------------------------------------------------------------------
// Layer 1 (MFMA, D = W x h): input F=10, hidden 70.
// Grid 256 = 2 dir x 128 tiles of 16 batch rows. 1024 threads = 16 waves
// (4 waves/SIMD). GEMM per step: [288 x 96] x [96 x 16] (18 real M-tiles).
//   wave w owns tile p = w; waves 0,1 also own tiles 16,17.
//   K: 0..69 = h, 70..79 = x, 80 = bias slot (B side 1.0), 81..95 = 0.
// D: lane n = batch m; 4 acc regs = 4 gates of cell u = 4p+quad.
// In-lane epilogue, double-buffered B-LDS, ONE barrier/step, x prefetch d=2.
// y1 layout: [T][256 subtiles of 8 rows][140][8] bf16.
// ---------------------------------------------------------------------------
__global__ __launch_bounds__(1024, 4) void k_lstm1(
    const float* __restrict__ x,
    const float* __restrict__ wih_f, const float* __restrict__ whh_f,
    const float* __restrict__ bih_f, const float* __restrict__ bhh_f,
    const float* __restrict__ wih_b, const float* __restrict__ whh_b,
    const float* __restrict__ bih_b, const float* __restrict__ bhh_b,
    unsigned short* __restrict__ y1)
{
    __shared__ short hB_hi[2][1536];   // 96 k x 16 batch, frag order, dbuf
    __shared__ short hB_lo[2][1536];

    const int tb  = blockIdx.x & 127;
    const int dir = blockIdx.x >> 7;
    const int b0  = tb << 4;
    const float* wih = dir ? wih_b : wih_f;
    const float* whh = dir ? whh_b : whh_f;
    const float* bih = dir ? bih_b : bih_f;
    const float* bhh = dir ? bhh_b : bhh_f;

    const int tid  = threadIdx.x;
    const int wv   = tid >> 6;
    const int lane = tid & 63;
    const int n    = lane & 15;
    const int quad = lane >> 4;
    const int NT1  = (wv < 2) ? 2 : 1;   // tiles this wave owns

    // ---- W-side (A-operand) preload, hi+lo bf16 ----
    short8 whi[2][3], wlo[2][3];
    const int g_ = n & 3;
#pragma unroll
    for (int tt = 0; tt < 2; ++tt) {
        if (tt < NT1) {
            const int p  = wv + 16 * tt;
            const int uu = 4 * p + (n >> 2);
#pragma unroll
            for (int q = 0; q < 3; ++q) {
#pragma unroll
                for (int j = 0; j < 8; ++j) {
                    int k = q * 32 + quad * 8 + j;
                    float v = 0.0f;
                    if (uu < H1) {
                        int row = g_ * H1 + uu;
                        if (k < H1)        v = whh[row * H1 + k];
                        else if (k < 80)   v = wih[row * Fz + (k - H1)];
                        else if (k == 80)  v = bih[row] + bhh[row];
                    }
                    unsigned short hi = f2bf(v);
                    unsigned short lo = f2bf(v - bf2f(hi));
                    whi[tt][q][j] = (short)hi;
                    wlo[tt][q][j] = (short)lo;
                }
            }
        }
    }

    // ---- init LDS ----
    for (int e = tid; e < 1536; e += 1024) {
        hB_hi[0][e] = 0; hB_lo[0][e] = 0;
        hB_hi[1][e] = 0; hB_lo[1][e] = 0;
    }
    __syncthreads();
    if (tid < 16) {
        int off = 1280 + tid * 8;       // frag_off(tid, 80)
        hB_hi[0][off] = (short)0x3F80;  // bf16(1.0) bias const
        hB_hi[1][off] = (short)0x3F80;
    }

    // ---- stager threads: es in [0,160) -> (m, f), threads 864..1023 ----
    const int es = tid - 864;
    const bool stg = (es >= 0 && es < 160);
    int sm = 0, sf = 0;
    if (stg) { sm = es / Fz; sf = es % Fz; }

    // prologue: stage x(t0) into buf 0; preload x(t1) into regs
    float xv = 0.0f;
    {
        const int t0 = dir ? (Tz - 1) : 0;
        if (stg) {
            float v = x[((size_t)(b0 + sm) * Tz + t0) * Fz + sf];
            unsigned short hi = f2bf(v);
            unsigned short lo = f2bf(v - bf2f(hi));
            int off = frag_off(sm, H1 + sf);
            hB_hi[0][off] = (short)hi;
            hB_lo[0][off] = (short)lo;
            const int t1 = dir ? (Tz - 2) : 1;
            xv = x[((size_t)(b0 + sm) * Tz + t1) * Fz + sf];
        }
    }

    float cst[2];
    cst[0] = 0.0f; cst[1] = 0.0f;

    for (int step = 0; step < Tz; ++step) {
        const int t  = dir ? (Tz - 1 - step) : step;
        const int pp = step & 1;
        __syncthreads();   // only barrier: buf[pp] complete, buf[pp^1] free

        // write x(t+1) from regs (no memory wait), then issue load x(t+2)
        if (stg && step + 1 < Tz) {
            unsigned short hi = f2bf(xv);
            unsigned short lo = f2bf(xv - bf2f(hi));
            int off = frag_off(sm, H1 + sf);
            hB_hi[pp ^ 1][off] = (short)hi;
            hB_lo[pp ^ 1][off] = (short)lo;
        }
        if (stg && step + 2 < Tz) {
            const int t2 = dir ? (t - 2) : (t + 2);
            xv = x[((size_t)(b0 + sm) * Tz + t2) * Fz + sf];
        }

        // B-operand frags from LDS
        short8 bhi[3], blo[3];
#pragma unroll
        for (int q = 0; q < 3; ++q) {
            bhi[q] = *(const short8*)&hB_hi[pp][q * 512 + lane * 8];
            blo[q] = *(const short8*)&hB_lo[pp][q * 512 + lane * 8];
        }

        // MFMA: per tile 9 products split into 2 independent chains (5+4)
        float4v accA[2], accB[2];
#pragma unroll
        for (int tt = 0; tt < 2; ++tt) {
            accA[tt] = (float4v){0.f, 0.f, 0.f, 0.f};
            accB[tt] = (float4v){0.f, 0.f, 0.f, 0.f};
        }
#pragma unroll
        for (int tt = 0; tt < 2; ++tt) {
            if (tt < NT1) {
                accA[tt] = MFMA16(whi[tt][0], bhi[0], accA[tt]);
                accB[tt] = MFMA16(whi[tt][0], blo[0], accB[tt]);
                accA[tt] = MFMA16(wlo[tt][0], bhi[0], accA[tt]);
                accB[tt] = MFMA16(whi[tt][1], bhi[1], accB[tt]);
                accA[tt] = MFMA16(whi[tt][1], blo[1], accA[tt]);
                accB[tt] = MFMA16(wlo[tt][1], bhi[1], accB[tt]);
                accA[tt] = MFMA16(whi[tt][2], bhi[2], accA[tt]);
                accB[tt] = MFMA16(whi[tt][2], blo[2], accB[tt]);
                accA[tt] = MFMA16(wlo[tt][2], bhi[2], accA[tt]);
            }
        }

        // in-lane epilogue: cell (m = n, u = 4p+quad)
#pragma unroll
        for (int tt = 0; tt < 2; ++tt) {
            if (tt < NT1) {
                const int p = wv + 16 * tt;
                const int u = 4 * p + quad;
                if (u < H1) {
                    float gi = accA[tt][0] + accB[tt][0];
                    float gf = accA[tt][1] + accB[tt][1];
                    float gc = accA[tt][2] + accB[tt][2];
                    float go = accA[tt][3] + accB[tt][3];
                    float cn = sigf(gf) * cst[tt] + sigf(gi) * tanhfast(gc);
                    float h  = sigf(go) * tanhfast(cn);
                    cst[tt] = cn;
                    unsigned short hh = f2bf(h);
                    unsigned short hl = f2bf(h - bf2f(hh));
                    int off = frag_off(n, u);
                    hB_hi[pp ^ 1][off] = (short)hh;
                    hB_lo[pp ^ 1][off] = (short)hl;
                    // y1 [T][256][140][8]: subtile = 2*tb + (n>>3), row = n&7
                    y1[((size_t)t * 256 + 2 * tb + (n >> 3)) * 1120
                       + (dir * H1 + u) * 8 + (n & 7)] = hh;
                }
            }
        }
    }
}

// ---------------------------------------------------------------------------
// Layer 2 (MFMA, D = W x h): input 140 (bf16 y1 [T][256][140][8]), hidden 21.
// Grid 256 = 256 tiles of 8 batch rows; BOTH directions per block.
// 1024 threads = 16 waves: waves 0..7 = fwd group, 8..15 = bwd group.
// Within a group (wvl = wv&7): wvl<6 compute tile p = wvl; wvl==6 stages x;
// wvl==7 idle. 3 compute waves/SIMD with independent chains.
// GEMM per step/dir: [96 x 192] x [192 x 16] (N cols 8..15 zero-padded).
//   K: 0..20 = h, 21 = bias slot, 22..31 = 0, 32..171 = x, 172..191 = 0.
// ---------------------------------------------------------------------------
__global__ __launch_bounds__(1024, 4) void k_lstm2(
    const unsigned short* __restrict__ y1,
    const float* __restrict__ wih_f, const float* __restrict__ whh_f,
    const float* __restrict__ bih_f, const float* __restrict__ bhh_f,
    const float* __restrict__ wih_b, const float* __restrict__ whh_b,
    const float* __restrict__ bih_b, const float* __restrict__ bhh_b,
    unsigned short* __restrict__ y2)   // [B][T][42] bf16
{
    __shared__ short hB_hi[2][2][3072];  // [dir group][buf]
    __shared__ short hB_lo[2][2][512];   // chunk 0 only (h lo)

    const int tb8 = blockIdx.x;          // 0..255, 8-row subtile
    const int b0  = tb8 << 3;

    const int tid  = threadIdx.x;
    const int wv   = tid >> 6;
    const int lane = tid & 63;
    const int n    = lane & 15;
    const int quad = lane >> 4;
    const int dg   = wv >> 3;            // 0 = fwd, 1 = bwd
    const int wvl  = wv & 7;
    const int dir  = dg;
    const bool comp = (wvl < 6);
    const bool stgw = (wvl == 6);

    const float* wih = dg ? wih_b : wih_f;
    const float* whh = dg ? whh_b : whh_f;
    const float* bih = dg ? bih_b : bih_f;
    const float* bhh = dg ? bhh_b : bhh_f;

    // ---- W-side preload (compute waves), hi+lo bf16 ----
    short8 whi[6], wlo[6];
    const int g_ = n & 3;
    if (comp) {
        const int uu = 4 * wvl + (n >> 2);
#pragma unroll
        for (int q = 0; q < 6; ++q) {
#pragma unroll
            for (int j = 0; j < 8; ++j) {
                int k = q * 32 + quad * 8 + j;
                float v = 0.0f;
                if (uu < H2) {
                    int row = g_ * H2 + uu;
                    if (k < H2)                   v = whh[row * H2 + k];
                    else if (k == 21)             v = bih[row] + bhh[row];
                    else if (k >= 32 && k < 172)  v = wih[row * 140 + (k - 32)];
                }
                unsigned short hi = f2bf(v);
                unsigned short lo = f2bf(v - bf2f(hi));
                whi[q][j] = (short)hi;
                wlo[q][j] = (short)lo;
            }
        }
    }

    // ---- init LDS ----
    for (int e = tid; e < 3072; e += 1024) {
        hB_hi[0][0][e] = 0; hB_hi[0][1][e] = 0;
        hB_hi[1][0][e] = 0; hB_hi[1][1][e] = 0;
    }
    if (tid < 512) {
        hB_lo[0][0][tid] = 0; hB_lo[0][1][tid] = 0;
        hB_lo[1][0][tid] = 0; hB_lo[1][1][tid] = 0;
    }
    __syncthreads();
    if (tid < 8) {
        int off = frag_off(tid, 21);
        hB_hi[0][0][off] = (short)0x3F80;  // bias const 1.0
        hB_hi[0][1][off] = (short)0x3F80;
        hB_hi[1][0][off] = (short)0x3F80;
        hB_hi[1][1][off] = (short)0x3F80;
    }

    // ---- stager wave (wvl==6): pair-tasks pt = lane (+64 if lane<6), pt<70.
    // pair pt covers input cols c = 2pt, 2pt+1 (k = 32+2pt, 32+2pt+1).
    const int npt = (lane < 6) ? 2 : 1;
    short8 xa[2], xb[2];   // prefetch regs (t+1)

    // prologue: stage x(t0) into buf 0; preload x(t1)
    if (stgw) {
        const int t0 = dir ? (Tz - 1) : 0;
        const int t1 = dir ? (Tz - 2) : 1;
#pragma unroll
        for (int i = 0; i < 2; ++i) {
            if (i < npt) {
                int pt = lane + 64 * i;
                size_t base = ((size_t)t0 * 256 + tb8) * 1120 + pt * 16;
                short8 va = *(const short8*)(y1 + base);
                short8 vb = *(const short8*)(y1 + base + 8);
#pragma unroll
                for (int j = 0; j < 8; ++j) {
                    ((unsigned int*)&hB_hi[dg][0][0])[frag_off(j, 32 + 2 * pt) >> 1] =
                        (unsigned int)(unsigned short)va[j] |
                        ((unsigned int)(unsigned short)vb[j] << 16);
                }
                size_t base1 = ((size_t)t1 * 256 + tb8) * 1120 + pt * 16;
                xa[i] = *(const short8*)(y1 + base1);
                xb[i] = *(const short8*)(y1 + base1 + 8);
            }
        }
    }

    float cst = 0.0f;

    for (int step = 0; step < Tz; ++step) {
        const int t  = dir ? (Tz - 1 - step) : step;
        const int pp = step & 1;
        __syncthreads();

        // stager: write x(t+1) from regs, then issue load x(t+2)
        if (stgw && step + 1 < Tz) {
#pragma unroll
            for (int i = 0; i < 2; ++i) {
                if (i < npt) {
                    int pt = lane + 64 * i;
#pragma unroll
                    for (int j = 0; j < 8; ++j) {
                        ((unsigned int*)&hB_hi[dg][pp ^ 1][0])[frag_off(j, 32 + 2 * pt) >> 1] =
                            (unsigned int)(unsigned short)xa[i][j] |
                            ((unsigned int)(unsigned short)xb[i][j] << 16);
                    }
                }
            }
        }
        if (stgw && step + 2 < Tz) {
            const int t2 = dir ? (t - 2) : (t + 2);
#pragma unroll
            for (int i = 0; i < 2; ++i) {
                if (i < npt) {
                    int pt = lane + 64 * i;
                    size_t base = ((size_t)t2 * 256 + tb8) * 1120 + pt * 16;
                    xa[i] = *(const short8*)(y1 + base);
                    xb[i] = *(const short8*)(y1 + base + 8);
                }
            }
        }

        if (comp) {
            // B-operand frags
            short8 bhi[6], blo0;
#pragma unroll
            for (int q = 0; q < 6; ++q)
                bhi[q] = *(const short8*)&hB_hi[dg][pp][q * 512 + lane * 8];
            blo0 = *(const short8*)&hB_lo[dg][pp][lane * 8];

            // 13 products split into 2 independent chains (7+6)
            float4v accA = (float4v){0.f, 0.f, 0.f, 0.f};
            float4v accB = (float4v){0.f, 0.f, 0.f, 0.f};
            accA = MFMA16(whi[0], bhi[0], accA);
            accB = MFMA16(whi[0], blo0,   accB);
            accA = MFMA16(wlo[0], bhi[0], accA);
            accB = MFMA16(whi[1], bhi[1], accB);
            accA = MFMA16(wlo[1], bhi[1], accA);
            accB = MFMA16(whi[2], bhi[2], accB);
            accA = MFMA16(wlo[2], bhi[2], accA);
            accB = MFMA16(whi[3], bhi[3], accB);
            accA = MFMA16(wlo[3], bhi[3], accA);
            accB = MFMA16(whi[4], bhi[4], accB);
            accA = MFMA16(wlo[4], bhi[4], accA);
            accB = MFMA16(whi[5], bhi[5], accB);
            accA = MFMA16(wlo[5], bhi[5], accA);

            // in-lane epilogue: cell (m = n < 8, u = 4wvl+quad)
            const int u = 4 * wvl + quad;
            if (u < H2 && n < 8) {
                float gi = accA[0] + accB[0];
                float gf = accA[1] + accB[1];
                float gc = accA[2] + accB[2];
                float go = accA[3] + accB[3];
                float cn = sigf(gf) * cst + sigf(gi) * tanhfast(gc);
                float h  = sigf(go) * tanhfast(cn);
                cst = cn;
                unsigned short hh = f2bf(h);
                unsigned short hl = f2bf(h - bf2f(hh));
                int off = frag_off(n, u);
                hB_hi[dg][pp ^ 1][off] = (short)hh;
                hB_lo[dg][pp ^ 1][off] = (short)hl;
                y2[((size_t)(b0 + n) * Tz + t) * 42 + dir * H2 + u] = hh;
            }
        }
    }
}

// ---------------------------------------------------------------------------
// Dense head: thread per (b,t). Weights via uniform scalar loads.
// ---------------------------------------------------------------------------
__global__ __launch_bounds__(256) void k_dense(
    const unsigned short* __restrict__ y2,
    const float* __restrict__ wd1, const float* __restrict__ bd1,
    const float* __restrict__ wd2, const float* __restrict__ bd2,
    const float* __restrict__ wo,  const float* __restrict__ bo,
    float* __restrict__ out)
{
    int idx = blockIdx.x * 256 + threadIdx.x;
    if (idx >= Bz * Tz) return;
    const unsigned int* row = (const unsigned int*)&y2[(size_t)idx * 42];

    float v[42];
#pragma unroll
    for (int j = 0; j < 21; ++j) {
        unsigned int p = row[j];
        v[2 * j]     = bf2f((unsigned short)(p & 0xFFFFu));
        v[2 * j + 1] = bf2f((unsigned short)(p >> 16));
    }

    float h1[30];
#pragma unroll
    for (int o = 0; o < 30; ++o) {
        float s = bd1[o];
#pragma unroll
        for (int j = 0; j < 42; ++j) s = fmaf(v[j], wd1[o * 42 + j], s);
        h1[o] = fmaxf(s, 0.0f);
    }
    float outv = bo[0];
#pragma unroll
    for (int o = 0; o < 20; ++o) {
        float s = bd2[o];
#pragma unroll
        for (int j = 0; j < 30; ++j) s = fmaf(h1[j], wd2[o * 30 + j], s);
        outv = fmaf(fmaxf(s, 0.0f), wo[o], outv);
    }
    out[idx] = outv;
}

// ---------------------------------------------------------------------------
extern "C" void kernel_launch(void* const* d_in, const int* in_sizes, int n_in,
                              void* d_out, int out_size, void* d_ws, size_t ws_size,
                              hipStream_t stream)
{
    const float* x      = (const float*)d_in[0];
    const float* w1f_ih = (const float*)d_in[1];
    const float* w1f_hh = (const float*)d_in[2];
    const float* b1f_ih = (const float*)d_in[3];
    const float* b1f_hh = (const float*)d_in[4];
    const float* w1b_ih = (const float*)d_in[5];
    const float* w1b_hh = (const float*)d_in[6];
    const float* b1b_ih = (const float*)d_in[7];
    const float* b1b_hh = (const float*)d_in[8];
    const float* w2f_ih = (const float*)d_in[9];
    const float* w2f_hh = (const float*)d_in[10];
    const float* b2f_ih = (const float*)d_in[11];
    const float* b2f_hh = (const float*)d_in[12];
    const float* w2b_ih = (const float*)d_in[13];
    const float* w2b_hh = (const float*)d_in[14];
    const float* b2b_ih = (const float*)d_in[15];
    const float* b2b_hh = (const float*)d_in[16];
    const float* wd1    = (const float*)d_in[17];
    const float* bd1    = (const float*)d_in[18];
    const float* wd2    = (const float*)d_in[19];
    const float* bd2    = (const float*)d_in[20];
    const float* wo     = (const float*)d_in[21];
    const float* bo     = (const float*)d_in[22];
    float* out = (float*)d_out;

    // Workspace: y1 bf16 [T][256][140][8] (192.7 MB) + y2 bf16 [B][T][42] (57.8 MB)
    const size_t y1_elems = (size_t)Tz * 256 * 1120;
    const size_t y2_elems = (size_t)Bz * Tz * 42;
    if (ws_size < (y1_elems + y2_elems) * 2) return;

    unsigned short* y1 = (unsigned short*)d_ws;
    unsigned short* y2 = y1 + y1_elems;

    hipLaunchKernelGGL(k_lstm1, dim3(256), dim3(1024), 0, stream,
                       x, w1f_ih, w1f_hh, b1f_ih, b1f_hh,
                       w1b_ih, w1b_hh, b1b_ih, b1b_hh, y1);
    hipLaunchKernelGGL(k_lstm2, dim3(256), dim3(1024), 0, stream,
                       y1, w2f_ih, w2f_hh, b2f_ih, b2f_hh,
                       w2b_ih, w2b_hh, b2b_ih, b2b_hh, y2);
    hipLaunchKernelGGL(k_dense, dim3((Bz * Tz + 255) / 256), dim3(256), 0, stream,
                       y2, wd1, bd1, wd2, bd2, wo, bo, out);
}

// Round 7
// 769.779 us; speedup vs baseline: 1.2590x; 1.2590x over previous
//
#include <hip/hip_runtime.h>

// Problem constants
#define Bz 2048
#define Tz 336
#define Fz 10
#define H1 70
#define H2 21

typedef __attribute__((ext_vector_type(8))) short short8;   // 8 bf16 = 4 VGPR
typedef __attribute__((ext_vector_type(4))) float float4v;  // MFMA acc

#define MFMA16(a, b, c) __builtin_amdgcn_mfma_f32_16x16x32_bf16((a), (b), (c), 0, 0, 0)

__device__ __forceinline__ float sigf(float x) {
    return 1.0f / (1.0f + __expf(-x));
}
__device__ __forceinline__ float tanhfast(float x) {
    float t = __expf(2.0f * x);
    return 1.0f - 2.0f / (t + 1.0f);
}
__device__ __forceinline__ unsigned short f2bf(float v) {
    unsigned int u = __float_as_uint(v);
    u += 0x7FFFu + ((u >> 16) & 1u);
    return (unsigned short)(u >> 16);
}
__device__ __forceinline__ float bf2f(unsigned short s) {
    return __uint_as_float(((unsigned int)s) << 16);
}

// Fragment-order LDS offset (in shorts) for (index-in-16 m, k):
// (m, k) lives at ((k>>3)*16 + m)*8 + (k&7)
__device__ __forceinline__ int frag_off(int m, int k) {
    return (k >> 3) * 128 + m * 8 + (k & 7);
}

// ---------------------------------------------------------------------------
// Layer 1 (MFMA, D = W x h): input F=10, hidden 70.
// Grid 256 = 2 dir x 128 tiles of 16 batch rows. 1024 threads = 16 waves.
// GEMM per step: [288 x 96] x [96 x 16] (18 real M-tiles, v = 4u+g).
//   wave w owns tile p = w; waves 0,1 also own tiles 16,17.
//   K: 0..69 = h, 70..79 = x, 80 = bias slot (B side 1.0), 81..95 = 0.
// h is bf16 (hi only) — B-operand reads are 3x b128/wave/step. W is hi+lo
// bf16 in registers (6 MFMA/tile). In-lane epilogue, dbuf B-LDS, ONE
// barrier/step, x prefetch depth 2. y1 layout: [T][128][140][16] bf16.
// ---------------------------------------------------------------------------
__global__ __launch_bounds__(1024, 4) void k_lstm1(
    const float* __restrict__ x,
    const float* __restrict__ wih_f, const float* __restrict__ whh_f,
    const float* __restrict__ bih_f, const float* __restrict__ bhh_f,
    const float* __restrict__ wih_b, const float* __restrict__ whh_b,
    const float* __restrict__ bih_b, const float* __restrict__ bhh_b,
    unsigned short* __restrict__ y1)
{
    __shared__ short hB_hi[2][1536];   // 96 k x 16 batch, frag order, dbuf

    const int tb  = blockIdx.x & 127;
    const int dir = blockIdx.x >> 7;
    const int b0  = tb << 4;
    const float* wih = dir ? wih_b : wih_f;
    const float* whh = dir ? whh_b : whh_f;
    const float* bih = dir ? bih_b : bih_f;
    const float* bhh = dir ? bhh_b : bhh_f;

    const int tid  = threadIdx.x;
    const int wv   = tid >> 6;
    const int lane = tid & 63;
    const int n    = lane & 15;
    const int quad = lane >> 4;
    const int NT1  = (wv < 2) ? 2 : 1;   // tiles this wave owns

    // ---- W-side (A-operand) preload, hi+lo bf16 ----
    short8 whi[2][3], wlo[2][3];
    const int g_ = n & 3;
#pragma unroll
    for (int tt = 0; tt < 2; ++tt) {
        if (tt < NT1) {
            const int p  = wv + 16 * tt;
            const int uu = 4 * p + (n >> 2);
#pragma unroll
            for (int q = 0; q < 3; ++q) {
#pragma unroll
                for (int j = 0; j < 8; ++j) {
                    int k = q * 32 + quad * 8 + j;
                    float v = 0.0f;
                    if (uu < H1) {
                        int row = g_ * H1 + uu;
                        if (k < H1)        v = whh[row * H1 + k];
                        else if (k < 80)   v = wih[row * Fz + (k - H1)];
                        else if (k == 80)  v = bih[row] + bhh[row];
                    }
                    unsigned short hi = f2bf(v);
                    unsigned short lo = f2bf(v - bf2f(hi));
                    whi[tt][q][j] = (short)hi;
                    wlo[tt][q][j] = (short)lo;
                }
            }
        }
    }

    // ---- init LDS ----
    for (int e = tid; e < 1536; e += 1024) {
        hB_hi[0][e] = 0; hB_hi[1][e] = 0;
    }
    __syncthreads();
    if (tid < 16) {
        int off = 1280 + tid * 8;       // frag_off(tid, 80)
        hB_hi[0][off] = (short)0x3F80;  // bf16(1.0) bias const
        hB_hi[1][off] = (short)0x3F80;
    }

    // ---- stager threads: es in [0,160) -> (m, f), threads 864..1023 ----
    const int es = tid - 864;
    const bool stg = (es >= 0 && es < 160);
    int sm = 0, sf = 0;
    if (stg) { sm = es / Fz; sf = es % Fz; }

    // prologue: stage x(t0) into buf 0; preload x(t1) into regs
    float xv = 0.0f;
    {
        const int t0 = dir ? (Tz - 1) : 0;
        if (stg) {
            float v = x[((size_t)(b0 + sm) * Tz + t0) * Fz + sf];
            hB_hi[0][frag_off(sm, H1 + sf)] = (short)f2bf(v);
            const int t1 = dir ? (Tz - 2) : 1;
            xv = x[((size_t)(b0 + sm) * Tz + t1) * Fz + sf];
        }
    }

    float cst[2];
    cst[0] = 0.0f; cst[1] = 0.0f;

    for (int step = 0; step < Tz; ++step) {
        const int t  = dir ? (Tz - 1 - step) : step;
        const int pp = step & 1;
        __syncthreads();   // only barrier: buf[pp] complete, buf[pp^1] free

        // write x(t+1) from regs (no memory wait), then issue load x(t+2)
        if (stg && step + 1 < Tz) {
            hB_hi[pp ^ 1][frag_off(sm, H1 + sf)] = (short)f2bf(xv);
        }
        if (stg && step + 2 < Tz) {
            const int t2 = dir ? (t - 2) : (t + 2);
            xv = x[((size_t)(b0 + sm) * Tz + t2) * Fz + sf];
        }

        // B-operand frags from LDS (hi only)
        short8 bhi[3];
#pragma unroll
        for (int q = 0; q < 3; ++q)
            bhi[q] = *(const short8*)&hB_hi[pp][q * 512 + lane * 8];

        // MFMA: per tile 6 products, 2 independent chains of 3
        float4v accA[2], accB[2];
#pragma unroll
        for (int tt = 0; tt < 2; ++tt) {
            accA[tt] = (float4v){0.f, 0.f, 0.f, 0.f};
            accB[tt] = (float4v){0.f, 0.f, 0.f, 0.f};
        }
#pragma unroll
        for (int tt = 0; tt < 2; ++tt) {
            if (tt < NT1) {
                accA[tt] = MFMA16(whi[tt][0], bhi[0], accA[tt]);
                accB[tt] = MFMA16(wlo[tt][0], bhi[0], accB[tt]);
                accA[tt] = MFMA16(whi[tt][1], bhi[1], accA[tt]);
                accB[tt] = MFMA16(wlo[tt][1], bhi[1], accB[tt]);
                accA[tt] = MFMA16(whi[tt][2], bhi[2], accA[tt]);
                accB[tt] = MFMA16(wlo[tt][2], bhi[2], accB[tt]);
            }
        }

        // in-lane epilogue: cell (m = n, u = 4p+quad)
#pragma unroll
        for (int tt = 0; tt < 2; ++tt) {
            if (tt < NT1) {
                const int p = wv + 16 * tt;
                const int u = 4 * p + quad;
                if (u < H1) {
                    float gi = accA[tt][0] + accB[tt][0];
                    float gf = accA[tt][1] + accB[tt][1];
                    float gc = accA[tt][2] + accB[tt][2];
                    float go = accA[tt][3] + accB[tt][3];
                    float cn = sigf(gf) * cst[tt] + sigf(gi) * tanhfast(gc);
                    float h  = sigf(go) * tanhfast(cn);
                    cst[tt] = cn;
                    unsigned short hh = f2bf(h);
                    hB_hi[pp ^ 1][frag_off(n, u)] = (short)hh;
                    y1[(((size_t)t * 128 + tb) * 140 + dir * H1 + u) * 16 + n] = hh;
                }
            }
        }
    }
}

// ---------------------------------------------------------------------------
// Layer 2 (MFMA, D = W x h): input 140 (bf16 y1 [T][128][140][16]), hidden 21.
// Grid 256 = 2 dir x 128 tiles of 16 rows. 512 threads = 8 waves.
//   waves 0..5 compute tile p = wv (u = 4p+quad); threads 232..511 stage x.
//   K: 0..20 = h, 21 = bias slot, 22..31 = 0, 32..171 = x, 172..191 = 0.
// h and x are bf16 (hi only); W is hi+lo (12 MFMA/wave). 6x b128 B-reads.
// ---------------------------------------------------------------------------
__global__ __launch_bounds__(512, 2) void k_lstm2(
    const unsigned short* __restrict__ y1,
    const float* __restrict__ wih_f, const float* __restrict__ whh_f,
    const float* __restrict__ bih_f, const float* __restrict__ bhh_f,
    const float* __restrict__ wih_b, const float* __restrict__ whh_b,
    const float* __restrict__ bih_b, const float* __restrict__ bhh_b,
    unsigned short* __restrict__ y2)   // [B][T][42] bf16
{
    __shared__ short hB_hi[2][3072];   // 192 k x 16 batch

    const int tb  = blockIdx.x & 127;
    const int dir = blockIdx.x >> 7;
    const int b0  = tb << 4;
    const float* wih = dir ? wih_b : wih_f;
    const float* whh = dir ? whh_b : whh_f;
    const float* bih = dir ? bih_b : bih_f;
    const float* bhh = dir ? bhh_b : bhh_f;

    const int tid  = threadIdx.x;
    const int wv   = tid >> 6;
    const int lane = tid & 63;
    const int n    = lane & 15;
    const int quad = lane >> 4;
    const bool comp = (wv < 6);

    // ---- W-side preload (waves 0..5), hi+lo bf16 ----
    short8 whi[6], wlo[6];
    const int g_ = n & 3;
    if (comp) {
        const int uu = 4 * wv + (n >> 2);
#pragma unroll
        for (int q = 0; q < 6; ++q) {
#pragma unroll
            for (int j = 0; j < 8; ++j) {
                int k = q * 32 + quad * 8 + j;
                float v = 0.0f;
                if (uu < H2) {
                    int row = g_ * H2 + uu;
                    if (k < H2)                   v = whh[row * H2 + k];
                    else if (k == 21)             v = bih[row] + bhh[row];
                    else if (k >= 32 && k < 172)  v = wih[row * 140 + (k - 32)];
                }
                unsigned short hi = f2bf(v);
                unsigned short lo = f2bf(v - bf2f(hi));
                whi[q][j] = (short)hi;
                wlo[q][j] = (short)lo;
            }
        }
    }

    // ---- init LDS ----
    for (int e = tid; e < 3072; e += 512) { hB_hi[0][e] = 0; hB_hi[1][e] = 0; }
    __syncthreads();
    if (tid < 16) {
        int off = frag_off(tid, 21);
        hB_hi[0][off] = (short)0x3F80;   // bias const 1.0
        hB_hi[1][off] = (short)0x3F80;
    }

    // ---- stager threads: es in [0,280); each loads 16B (8 ushorts) ----
    const int es = tid - 232;
    const bool stg = (es >= 0 && es < 280);

    // prologue: stage x(t0) into buf 0; preload x(t1) into regs
    short8 xr = (short8){0,0,0,0,0,0,0,0};
    {
        const int t0 = dir ? (Tz - 1) : 0;
        if (stg) {
            short8 v = *(const short8*)(y1 + ((size_t)t0 * 128 + tb) * 2240 + es * 8);
#pragma unroll
            for (int j = 0; j < 8; ++j) {
                int idx = es * 8 + j;
                hB_hi[0][frag_off(idx & 15, 32 + (idx >> 4))] = v[j];
            }
            const int t1 = dir ? (Tz - 2) : 1;
            xr = *(const short8*)(y1 + ((size_t)t1 * 128 + tb) * 2240 + es * 8);
        }
    }

    float cst = 0.0f;

    for (int step = 0; step < Tz; ++step) {
        const int t  = dir ? (Tz - 1 - step) : step;
        const int pp = step & 1;
        __syncthreads();

        // write x(t+1) from regs, then issue load x(t+2)
        if (stg && step + 1 < Tz) {
#pragma unroll
            for (int j = 0; j < 8; ++j) {
                int idx = es * 8 + j;
                hB_hi[pp ^ 1][frag_off(idx & 15, 32 + (idx >> 4))] = xr[j];
            }
        }
        if (stg && step + 2 < Tz) {
            const int t2 = dir ? (t - 2) : (t + 2);
            xr = *(const short8*)(y1 + ((size_t)t2 * 128 + tb) * 2240 + es * 8);
        }

        if (comp) {
            // B-operand frags (hi only)
            short8 bhi[6];
#pragma unroll
            for (int q = 0; q < 6; ++q)
                bhi[q] = *(const short8*)&hB_hi[pp][q * 512 + lane * 8];

            // 12 products, 2 independent chains of 6
            float4v accA = (float4v){0.f, 0.f, 0.f, 0.f};
            float4v accB = (float4v){0.f, 0.f, 0.f, 0.f};
#pragma unroll
            for (int q = 0; q < 6; ++q) {
                accA = MFMA16(whi[q], bhi[q], accA);
                accB = MFMA16(wlo[q], bhi[q], accB);
            }

            // in-lane epilogue: cell (m = n, u = 4wv+quad)
            const int u = 4 * wv + quad;
            if (u < H2) {
                float gi = accA[0] + accB[0];
                float gf = accA[1] + accB[1];
                float gc = accA[2] + accB[2];
                float go = accA[3] + accB[3];
                float cn = sigf(gf) * cst + sigf(gi) * tanhfast(gc);
                float h  = sigf(go) * tanhfast(cn);
                cst = cn;
                unsigned short hh = f2bf(h);
                hB_hi[pp ^ 1][frag_off(n, u)] = (short)hh;
                y2[((size_t)(b0 + n) * Tz + t) * 42 + dir * H2 + u] = hh;
            }
        }
    }
}

// ---------------------------------------------------------------------------
// Dense head: thread per (b,t). Weights via uniform scalar loads.
// ---------------------------------------------------------------------------
__global__ __launch_bounds__(256) void k_dense(
    const unsigned short* __restrict__ y2,
    const float* __restrict__ wd1, const float* __restrict__ bd1,
    const float* __restrict__ wd2, const float* __restrict__ bd2,
    const float* __restrict__ wo,  const float* __restrict__ bo,
    float* __restrict__ out)
{
    int idx = blockIdx.x * 256 + threadIdx.x;
    if (idx >= Bz * Tz) return;
    const unsigned int* row = (const unsigned int*)&y2[(size_t)idx * 42];

    float v[42];
#pragma unroll
    for (int j = 0; j < 21; ++j) {
        unsigned int p = row[j];
        v[2 * j]     = bf2f((unsigned short)(p & 0xFFFFu));
        v[2 * j + 1] = bf2f((unsigned short)(p >> 16));
    }

    float h1[30];
#pragma unroll
    for (int o = 0; o < 30; ++o) {
        float s = bd1[o];
#pragma unroll
        for (int j = 0; j < 42; ++j) s = fmaf(v[j], wd1[o * 42 + j], s);
        h1[o] = fmaxf(s, 0.0f);
    }
    float outv = bo[0];
#pragma unroll
    for (int o = 0; o < 20; ++o) {
        float s = bd2[o];
#pragma unroll
        for (int j = 0; j < 30; ++j) s = fmaf(h1[j], wd2[o * 30 + j], s);
        outv = fmaf(fmaxf(s, 0.0f), wo[o], outv);
    }
    out[idx] = outv;
}

// ---------------------------------------------------------------------------
extern "C" void kernel_launch(void* const* d_in, const int* in_sizes, int n_in,
                              void* d_out, int out_size, void* d_ws, size_t ws_size,
                              hipStream_t stream)
{
    const float* x      = (const float*)d_in[0];
    const float* w1f_ih = (const float*)d_in[1];
    const float* w1f_hh = (const float*)d_in[2];
    const float* b1f_ih = (const float*)d_in[3];
    const float* b1f_hh = (const float*)d_in[4];
    const float* w1b_ih = (const float*)d_in[5];
    const float* w1b_hh = (const float*)d_in[6];
    const float* b1b_ih = (const float*)d_in[7];
    const float* b1b_hh = (const float*)d_in[8];
    const float* w2f_ih = (const float*)d_in[9];
    const float* w2f_hh = (const float*)d_in[10];
    const float* b2f_ih = (const float*)d_in[11];
    const float* b2f_hh = (const float*)d_in[12];
    const float* w2b_ih = (const float*)d_in[13];
    const float* w2b_hh = (const float*)d_in[14];
    const float* b2b_ih = (const float*)d_in[15];
    const float* b2b_hh = (const float*)d_in[16];
    const float* wd1    = (const float*)d_in[17];
    const float* bd1    = (const float*)d_in[18];
    const float* wd2    = (const float*)d_in[19];
    const float* bd2    = (const float*)d_in[20];
    const float* wo     = (const float*)d_in[21];
    const float* bo     = (const float*)d_in[22];
    float* out = (float*)d_out;

    // Workspace: y1 bf16 [T][128][140][16] (192.7 MB) + y2 bf16 [B][T][42] (57.8 MB)
    const size_t y1_elems = (size_t)Tz * 128 * 2240;
    const size_t y2_elems = (size_t)Bz * Tz * 42;
    if (ws_size < (y1_elems + y2_elems) * 2) return;

    unsigned short* y1 = (unsigned short*)d_ws;
    unsigned short* y2 = y1 + y1_elems;

    hipLaunchKernelGGL(k_lstm1, dim3(256), dim3(1024), 0, stream,
                       x, w1f_ih, w1f_hh, b1f_ih, b1f_hh,
                       w1b_ih, w1b_hh, b1b_ih, b1b_hh, y1);
    hipLaunchKernelGGL(k_lstm2, dim3(256), dim3(512), 0, stream,
                       y1, w2f_ih, w2f_hh, b2f_ih, b2f_hh,
                       w2b_ih, w2b_hh, b2b_ih, b2b_hh, y2);
    hipLaunchKernelGGL(k_dense, dim3((Bz * Tz + 255) / 256), dim3(256), 0, stream,
                       y2, wd1, bd1, wd2, bd2, wo, bo, out);
}